// Round 10
// baseline (584.821 us; speedup 1.0000x reference)
//
#include <hip/hip_runtime.h>
#include <cstdint>
#include <cstddef>

#define MROWS 16384     // B*R = 32*512
#define INDIM 1024
#define DD    256
#define TWO_D 512
#define KC    4096
#define OUTD  1024
#define NZQ   (MROWS * OUTD)   // 16777216

typedef short bfrag __attribute__((ext_vector_type(8)));   // 8 bf16 (4 VGPRs)
typedef float ffrag __attribute__((ext_vector_type(4)));   // 4 fp32 acc

__device__ __forceinline__ ushort f2bf(float f) {          // RNE f32->bf16
    uint u = __float_as_uint(f);
    return (ushort)((u + 0x7FFFu + ((u >> 16) & 1u)) >> 16);
}

// async global->LDS, 16B per lane, dest = wave-uniform base + lane*16
#define GLD16(dst, src)                                                        \
    __builtin_amdgcn_global_load_lds(                                          \
        (const __attribute__((address_space(1))) unsigned int*)(src),          \
        (__attribute__((address_space(3))) unsigned int*)(dst), 16, 0, 0)

// ---------------------------------------------------------------------------
// K1: h = z @ W_qa + b_qa (fp32, strict k-ascending FMA chain -> bit-exact;
// LOAD-BEARING). R3 structure (verified 225-229us): 128x128 tile, 8x8 micro,
// 256 thr, global_load_lds dbuf staging, 1 barrier/step.
// Epilogue emits Rnp[by][row] partial row-norm (deterministic butterfly).
// R7 lesson: no heterogeneous co-dispatch. Grid (128, 4), block 256.
// ---------------------------------------------------------------------------
__global__ __launch_bounds__(256) void k_gemm1(const float* __restrict__ z,
                                               const float* __restrict__ Wqa,
                                               const float* __restrict__ bqa,
                                               float* __restrict__ h,
                                               ushort* __restrict__ hbf,
                                               float* __restrict__ Rnp) {
    __shared__ float As[2][128][16];   // 16 KB  [buf][row][k] (k-quads swizzled)
    __shared__ float Bs[2][16][128];   // 16 KB  [buf][k][col] linear
    const int tid = threadIdx.x;
    const int l = tid & 63, w = tid >> 6;
    const int tx = tid & 15, ty = tid >> 4;
    const int rb = blockIdx.x * 128;
    const int cb = blockIdx.y * 128;

    float acc[8][8] = {};

    const int sA = 4 * ((l & 3) ^ ((l >> 4) & 3));
    const float* aA0 = z + (size_t)(rb + 32 * w + (l >> 2)) * INDIM + sA;
    const float* aA1 = aA0 + (size_t)16 * INDIM;
    const float* bB0 = Wqa + (size_t)(4 * w + (l >> 5)) * TWO_D + cb + (l & 31) * 4;
    const float* bB1 = bB0 + (size_t)2 * TWO_D;

#define STAGE(buf, k0)                                                         \
    do {                                                                       \
        GLD16(&As[buf][32 * w][0],      aA0 + (k0));                           \
        GLD16(&As[buf][32 * w + 16][0], aA1 + (k0));                           \
        GLD16(&Bs[buf][4 * w][0],       bB0 + (size_t)(k0) * TWO_D);           \
        GLD16(&Bs[buf][4 * w + 2][0],   bB1 + (size_t)(k0) * TWO_D);           \
    } while (0)

    STAGE(0, 0);
    __syncthreads();

    const int xk = ty & 3;    // read-side XOR key = (row>>2)&3 for all 8 rows
    for (int t = 0; t < 64; ++t) {
        const int cur = t & 1;
        if (t < 63) STAGE(cur ^ 1, (t + 1) * 16);   // async, lands by barrier
        #pragma unroll
        for (int q = 0; q < 4; ++q) {               // k-quad
            float fa[8][4];
            #pragma unroll
            for (int i = 0; i < 4; ++i) {
                *reinterpret_cast<float4*>(&fa[i][0]) =
                    *reinterpret_cast<const float4*>(&As[cur][ty * 4 + i][(q ^ xk) * 4]);
                *reinterpret_cast<float4*>(&fa[4 + i][0]) =
                    *reinterpret_cast<const float4*>(&As[cur][64 + ty * 4 + i][(q ^ xk) * 4]);
            }
            #pragma unroll
            for (int c = 0; c < 4; ++c) {           // kk = 4q+c, ascending
                const int kk = q * 4 + c;
                float4 b0 = *reinterpret_cast<const float4*>(&Bs[cur][kk][tx * 4]);
                float4 b1 = *reinterpret_cast<const float4*>(&Bs[cur][kk][64 + tx * 4]);
                float bv[8] = {b0.x, b0.y, b0.z, b0.w, b1.x, b1.y, b1.z, b1.w};
                #pragma unroll
                for (int i = 0; i < 8; ++i)
                    #pragma unroll
                    for (int j = 0; j < 8; ++j)
                        acc[i][j] = fmaf(fa[i][c], bv[j], acc[i][j]);
            }
        }
        __syncthreads();   // drains this wave's STAGE vmcnt + orders LDS reuse
    }
#undef STAGE

    #pragma unroll
    for (int i = 0; i < 8; ++i) {
        const int row = rb + ((i < 4) ? (ty * 4 + i) : (64 + ty * 4 + i - 4));
        float rsum = 0.f;
        #pragma unroll
        for (int jh = 0; jh < 2; ++jh) {
            const int col = cb + jh * 64 + tx * 4;
            float v0 = acc[i][jh * 4 + 0] + bqa[col + 0];
            float v1 = acc[i][jh * 4 + 1] + bqa[col + 1];
            float v2 = acc[i][jh * 4 + 2] + bqa[col + 2];
            float v3 = acc[i][jh * 4 + 3] + bqa[col + 3];
            float4 vf = {v0, v1, v2, v3};
            *reinterpret_cast<float4*>(&h[(size_t)row * TWO_D + col]) = vf;
            ushort u[4] = {f2bf(v0), f2bf(v1), f2bf(v2), f2bf(v3)};
            *reinterpret_cast<uint2*>(&hbf[(size_t)row * TWO_D + col]) =
                *reinterpret_cast<uint2*>(u);
            rsum += v0 * v0 + v1 * v1 + v2 * v2 + v3 * v3;
        }
        // 16-lane butterfly over tx (fixed order, deterministic)
        #pragma unroll
        for (int off = 1; off < 16; off <<= 1) rsum += __shfl_xor(rsum, off, 16);
        if (tx == 0) Rnp[(size_t)blockIdx.y * MROWS + row] = rsum;
    }
}

// ---------------------------------------------------------------------------
// K3: fused bf16 converts. Blocks [0,2048): emb1|emb2 -> ebf + Ren (per-wave
// one codebook row). Blocks [2048,2560): W_pq -> transposed bf16.
// Grid 2560, block 256.
// ---------------------------------------------------------------------------
__global__ __launch_bounds__(256) void k_cvt(const float* __restrict__ e1,
                                             const float* __restrict__ e2,
                                             const float* __restrict__ Wpq,
                                             ushort* __restrict__ ebf,
                                             ushort* __restrict__ wbfT,
                                             float* __restrict__ Ren) {
    const int b = blockIdx.x;
    const int tid = threadIdx.x;
    if (b < 2048) {
        const size_t v = ((size_t)b * 256 + tid) * 4;
        const size_t half = (size_t)KC * DD;
        const float* src = (v < half) ? (e1 + v) : (e2 + (v - half));
        float4 f = *reinterpret_cast<const float4*>(src);
        ebf[v + 0] = f2bf(f.x); ebf[v + 1] = f2bf(f.y);
        ebf[v + 2] = f2bf(f.z); ebf[v + 3] = f2bf(f.w);
        float ss = f.x * f.x + f.y * f.y + f.z * f.z + f.w * f.w;
        #pragma unroll
        for (int off = 32; off; off >>= 1) ss += __shfl_down(ss, off, 64);
        if ((tid & 63) == 0) Ren[b * 4 + (tid >> 6)] = ss;
    } else {
        const int e = ((b - 2048) * 256 + tid) * 4;   // 0..524284
        const int k = e >> 10, c = e & 1023;
        float4 f = *reinterpret_cast<const float4*>(&Wpq[e]);
        wbfT[(size_t)(c + 0) * TWO_D + k] = f2bf(f.x);
        wbfT[(size_t)(c + 1) * TWO_D + k] = f2bf(f.y);
        wbfT[(size_t)(c + 2) * TWO_D + k] = f2bf(f.z);
        wbfT[(size_t)(c + 3) * TWO_D + k] = f2bf(f.w);
    }
}

// ---------------------------------------------------------------------------
// K4: MFMA score pass (selection only). C[row,code] = <h_bf, e_bf>, bf16
// 16x16x32 MFMA. R10: 128x256 tile, 512 threads (8 waves x 64x64), K=256 in
// 8 chunks. hbf re-read passes halve (32->16), block count halves (prologue/
// epilogue amortized 2x), 3 GLD16/wave/chunk (was 4). LDS 48KB -> 3 blk/CU.
// Staging slot s = w>>1, row-half (w&1): A 1 GLD16, B 2 GLD16 per wave.
// Source octet pre-swizzle ((w>>1) ^ ((l>>1)&3)) — row offsets 64/128 = 0
// mod 8 keep the (l>>1)&3 term valid. Read path identical to R5-verified.
// cand semantics IDENTICAL: seg = 64-col group = by*4 + (w>>1), 64 segs/cbk,
// item-major cand[(cbk*MROWS+row)*128 + seg*2]. Grid (128,16,2), block 512.
// ---------------------------------------------------------------------------
__global__ __launch_bounds__(512) void k_score_mfma(const ushort* __restrict__ hbf,
                                                    const ushort* __restrict__ ebf,
                                                    uint* __restrict__ cand) {
    __shared__ ushort Ab[2][4][128][8];   // 16 KB
    __shared__ ushort Bb[2][4][256][8];   // 32 KB
    const int tid = threadIdx.x;
    const int l = tid & 63, w = tid >> 6;          // w = 0..7
    const int rb    = blockIdx.x * 128;
    const int cbcol = blockIdx.y * 256;
    const int cbk   = blockIdx.z;
    const ushort* hb = hbf + cbk * DD;                 // row stride TWO_D
    const ushort* eb = ebf + (size_t)cbk * KC * DD;    // row stride DD

    const int ry = (w & 1) * 64;          // 2 row groups
    const int cy = (w >> 1) * 64;         // 4 col groups (256 cols)

    // staging: slot s = w>>1, row-half rh = (w&1)*64.
    // Ab[s][r] holds octet s ^ ((r>>1)&3) of row r (R5-verified content).
    const int s0   = w >> 1;
    const int rh   = (w & 1) * 64;
    const int koct = (s0 ^ ((l >> 1) & 3)) * 8;
    const ushort* aS  = hb + (size_t)(rb + rh + l) * TWO_D + koct;        // A rows rh..rh+63
    const ushort* bSa = eb + (size_t)(cbcol + rh + l) * DD + koct;        // B rows rh..rh+63
    const ushort* bSb = eb + (size_t)(cbcol + 128 + rh + l) * DD + koct;  // B rows 128+rh..

#define SSTAGE(buf, k0)                                                        \
    do {                                                                       \
        GLD16(&Ab[buf][s0][rh][0],        aS  + (k0));                         \
        GLD16(&Bb[buf][s0][rh][0],        bSa + (k0));                         \
        GLD16(&Bb[buf][s0][128 + rh][0],  bSb + (k0));                         \
    } while (0)

    ffrag acc[4][4];
    #pragma unroll
    for (int i = 0; i < 4; ++i)
        #pragma unroll
        for (int j = 0; j < 4; ++j)
            acc[i][j] = (ffrag){0.f, 0.f, 0.f, 0.f};

    SSTAGE(0, 0);
    __syncthreads();

    const int q = l >> 4, li = l & 15;
    for (int c = 0; c < 8; ++c) {
        const int cur = c & 1;
        if (c < 7) SSTAGE(cur ^ 1, (c + 1) * 32);   // async, drained by barrier
        bfrag afr[4], bfr[4];
        #pragma unroll
        for (int rf = 0; rf < 4; ++rf) {
            const int r = ry + rf * 16 + li;
            afr[rf] = *reinterpret_cast<const bfrag*>(&Ab[cur][q ^ ((r >> 1) & 3)][r][0]);
        }
        #pragma unroll
        for (int cf = 0; cf < 4; ++cf) {
            const int cc = cy + cf * 16 + li;
            bfr[cf] = *reinterpret_cast<const bfrag*>(&Bb[cur][q ^ ((cc >> 1) & 3)][cc][0]);
        }
        #pragma unroll
        for (int rf = 0; rf < 4; ++rf)
            #pragma unroll
            for (int cf = 0; cf < 4; ++cf)
                acc[rf][cf] = __builtin_amdgcn_mfma_f32_16x16x32_bf16(afr[rf], bfr[cf],
                                                                      acc[rf][cf], 0, 0, 0);
        __syncthreads();
    }
#undef SSTAGE

    const int seg = blockIdx.y * 4 + (w >> 1);      // 64-col group, 0..63
    #pragma unroll
    for (int rf = 0; rf < 4; ++rf) {
        #pragma unroll
        for (int reg = 0; reg < 4; ++reg) {
            const int row = rb + ry + rf * 16 + q * 4 + reg;
            uint k1 = 0, k2 = 0;
            #pragma unroll
            for (int cf = 0; cf < 4; ++cf) {
                float v = acc[rf][cf][reg];
                const int code = cbcol + cy + cf * 16 + li;
                uint u = __float_as_uint(v);
                u ^= (0x80000000u | (uint)((int)u >> 31));      // order-preserving flip
                const uint key = (u & 0xFFFFF000u) | (uint)code;
                if (key > k1) { k2 = k1; k1 = key; }
                else if (key > k2) { k2 = key; }
            }
            #pragma unroll
            for (int m = 1; m < 16; m <<= 1) {
                uint o1 = __shfl_xor((int)k1, m, 64);
                uint o2 = __shfl_xor((int)k2, m, 64);
                uint n1 = k1 > o1 ? k1 : o1;
                uint lo = k1 > o1 ? o1 : k1;
                uint hi2 = k2 > o2 ? k2 : o2;
                k2 = lo > hi2 ? lo : hi2;
                k1 = n1;
            }
            if (li == 0) {
                const size_t base = ((size_t)cbk * MROWS + row) * 128 + seg * 2;
                cand[base] = k1; cand[base + 1] = k2;
            }
        }
    }
}

// ---------------------------------------------------------------------------
// K5: reduce. One wave = 8 items x 8 candidate lanes (R6-verified). Per item:
// 128 contiguous keys -> top-8 via 8 rounds; each lane one exact fp32 dot
// (float4 loads, x,y,z,w fmaf order = sequential d-ascending chain).
// Rn = Rnp[2cb]+Rnp[2cb+1] (fixed order). d = Rn - 2M; lexicographic
// (d,code) min. Winner emits lossb = d + Ren[code]. Grid 1024, block 256.
// ---------------------------------------------------------------------------
__global__ __launch_bounds__(256) void k_reduce(const uint* __restrict__ cand,
                                                const float* __restrict__ h,
                                                const float* __restrict__ emb1,
                                                const float* __restrict__ emb2,
                                                const float* __restrict__ Rnp,
                                                const float* __restrict__ Ren,
                                                float* __restrict__ dout_idx,
                                                float* __restrict__ lossb) {
    const int tid = threadIdx.x;
    const int l = tid & 63, w = tid >> 6;
    const int g = l & 7;                       // candidate slot within item
    const int item = blockIdx.x * 32 + w * 8 + (l >> 3);
    const int cb  = item >> 14;
    const int row = item & (MROWS - 1);

    const uint* kp = cand + (size_t)item * 128 + g * 16;
    uint k[16];
    #pragma unroll
    for (int j = 0; j < 4; ++j) {
        uint4 v = *reinterpret_cast<const uint4*>(kp + j * 4);
        k[j * 4 + 0] = v.x; k[j * 4 + 1] = v.y;
        k[j * 4 + 2] = v.z; k[j * 4 + 3] = v.w;
    }

    uint mykey = 0;
    #pragma unroll
    for (int t = 0; t < 8; ++t) {
        uint m = k[0];
        #pragma unroll
        for (int j = 1; j < 16; ++j) m = k[j] > m ? k[j] : m;
        #pragma unroll
        for (int off = 1; off < 8; off <<= 1) {
            uint o = (uint)__shfl_xor((int)m, off, 64);
            m = o > m ? o : m;
        }
        #pragma unroll
        for (int j = 0; j < 16; ++j) k[j] = (k[j] == m) ? 0u : k[j];
        if (g == t) mykey = m;
    }

    const int code = (int)(mykey & 0xFFFu);
    const float* hr = h + (size_t)row * TWO_D + cb * DD;
    const float* er = (cb ? emb2 : emb1) + (size_t)code * DD;
    float M = 0.f;
    for (int d = 0; d < DD; d += 4) {        // sequential chain, vector loads
        float4 a = *reinterpret_cast<const float4*>(hr + d);
        float4 b = *reinterpret_cast<const float4*>(er + d);
        M = fmaf(a.x, b.x, M); M = fmaf(a.y, b.y, M);
        M = fmaf(a.z, b.z, M); M = fmaf(a.w, b.w, M);
    }
    const float Rn = Rnp[(size_t)(2 * cb) * MROWS + row] +
                     Rnp[(size_t)(2 * cb + 1) * MROWS + row];
    float dd = Rn - 2.0f * M;
    int c2 = code;
    #pragma unroll
    for (int off = 1; off < 8; off <<= 1) {
        float od = __shfl_xor(dd, off, 64);
        int   oc = __shfl_xor(c2, off, 64);
        if (od < dd || (od == dd && oc < c2)) { dd = od; c2 = oc; }
    }
    if (g == 0) {
        dout_idx[cb * MROWS + row] = (float)c2;
        lossb[cb * MROWS + row] = dd + Ren[cb * KC + c2];
    }
}

// ---------------------------------------------------------------------------
// K6: combine per-half loss partials. Grid 64, block 256.
// ---------------------------------------------------------------------------
__global__ __launch_bounds__(256) void k_loss2(const float* __restrict__ lossb,
                                               float* __restrict__ dout_loss) {
    const int r = blockIdx.x * 256 + threadIdx.x;
    dout_loss[r] = (lossb[r] + lossb[MROWS + r]) * (0.625f / 256.0f);
}

// ---------------------------------------------------------------------------
// K7: out = gather(e_bf, idx) @ W_pq_bf + b_pq via MFMA (bf16 in, fp32 out).
// global_load_lds dbuf pipeline, source-side octet swizzle (R5-verified).
// Grid (128, 8), block 256.
// ---------------------------------------------------------------------------
__global__ __launch_bounds__(256) void k_gemm2m(const ushort* __restrict__ ebf,
                                                const ushort* __restrict__ wbfT,
                                                const float* __restrict__ idxf,
                                                const float* __restrict__ bpq,
                                                float* __restrict__ out) {
    __shared__ ushort Ab[2][4][128][8];   // 16 KB
    __shared__ ushort Bb[2][4][128][8];   // 16 KB
    const int tid = threadIdx.x;
    const int l = tid & 63, w = tid >> 6;
    const int rb    = blockIdx.x * 128;
    const int cbcol = blockIdx.y * 128;
    const int ry = (w & 1) * 64;
    const int cy = (w >> 1) * 64;
    const ushort* e1 = ebf;
    const ushort* e2 = ebf + (size_t)KC * DD;

    const int ia0 = (int)idxf[rb + l];
    const int ia1 = (int)idxf[rb + 64 + l];
    const int ib0 = (int)idxf[MROWS + rb + l];
    const int ib1 = (int)idxf[MROWS + rb + 64 + l];

    const int koct = (w ^ ((l >> 1) & 3)) * 8;
    const ushort* aA0 = e1 + (size_t)ia0 * DD + koct;   // half 0, rows it=0
    const ushort* aA1 = e1 + (size_t)ia1 * DD + koct;   // half 0, rows it=1
    const ushort* aB0 = e2 + (size_t)ib0 * DD + koct;   // half 1
    const ushort* aB1 = e2 + (size_t)ib1 * DD + koct;
    const ushort* bS0 = wbfT + (size_t)(cbcol + l) * TWO_D + koct;
    const ushort* bS1 = wbfT + (size_t)(cbcol + 64 + l) * TWO_D + koct;

#define GSTAGE(buf, c)                                                         \
    do {                                                                       \
        const int cbs_ = (c) >> 3;                                             \
        const int ka_  = ((c) * 32) & 255;                                     \
        GLD16(&Ab[buf][w][0][0],  (cbs_ ? aB0 : aA0) + ka_);                   \
        GLD16(&Ab[buf][w][64][0], (cbs_ ? aB1 : aA1) + ka_);                   \
        GLD16(&Bb[buf][w][0][0],  bS0 + (c) * 32);                             \
        GLD16(&Bb[buf][w][64][0], bS1 + (c) * 32);                             \
    } while (0)

    ffrag acc[4][4];
    #pragma unroll
    for (int i = 0; i < 4; ++i)
        #pragma unroll
        for (int j = 0; j < 4; ++j)
            acc[i][j] = (ffrag){0.f, 0.f, 0.f, 0.f};

    GSTAGE(0, 0);
    __syncthreads();

    const int q = l >> 4, li = l & 15;
    for (int c = 0; c < 16; ++c) {
        const int cur = c & 1;
        if (c < 15) GSTAGE(cur ^ 1, c + 1);   // async, drained by barrier
        bfrag afr[4], bfr[4];
        #pragma unroll
        for (int rf = 0; rf < 4; ++rf) {
            const int r = ry + rf * 16 + li;
            afr[rf] = *reinterpret_cast<const bfrag*>(&Ab[cur][q ^ ((r >> 1) & 3)][r][0]);
        }
        #pragma unroll
        for (int cf = 0; cf < 4; ++cf) {
            const int cc = cy + cf * 16 + li;
            bfr[cf] = *reinterpret_cast<const bfrag*>(&Bb[cur][q ^ ((cc >> 1) & 3)][cc][0]);
        }
        #pragma unroll
        for (int rf = 0; rf < 4; ++rf)
            #pragma unroll
            for (int cf = 0; cf < 4; ++cf)
                acc[rf][cf] = __builtin_amdgcn_mfma_f32_16x16x32_bf16(afr[rf], bfr[cf],
                                                                      acc[rf][cf], 0, 0, 0);
        __syncthreads();
    }
#undef GSTAGE

    #pragma unroll
    for (int rf = 0; rf < 4; ++rf) {
        #pragma unroll
        for (int reg = 0; reg < 4; ++reg) {
            const int row = rb + ry + rf * 16 + q * 4 + reg;
            #pragma unroll
            for (int cf = 0; cf < 4; ++cf) {
                const int col = cbcol + cy + cf * 16 + li;
                out[(size_t)row * OUTD + col] = acc[rf][cf][reg] + bpq[col];
            }
        }
    }
}

// ---------------------------------------------------------------------------
extern "C" void kernel_launch(void* const* d_in, const int* in_sizes, int n_in,
                              void* d_out, int out_size, void* d_ws, size_t ws_size,
                              hipStream_t stream) {
    const float* z    = (const float*)d_in[0];
    const float* Wqa  = (const float*)d_in[1];
    const float* bqa  = (const float*)d_in[2];
    const float* emb1 = (const float*)d_in[3];
    const float* emb2 = (const float*)d_in[4];
    const float* Wpq  = (const float*)d_in[5];
    const float* bpq  = (const float*)d_in[6];
    float* out = (float*)d_out;

    const size_t H = (size_t)MROWS * TWO_D;        // 8,388,608
    float*  hbuf  = (float*)d_ws;                  // [H]            33.55 MB
    float*  Rnp   = hbuf + H;                      // [4*MROWS]       0.26 MB
    float*  lossb = Rnp + 4 * MROWS;               // [2*MROWS]       0.13 MB
    float*  Ren   = lossb + 2 * MROWS;             // [2*KC]          0.03 MB
    ushort* hbf   = (ushort*)(Ren + 2 * KC);       // [H]            16.78 MB
    ushort* ebf   = hbf + H;                       // [2*KC*DD]       4.19 MB
    ushort* wbfT  = ebf + 2 * (size_t)KC * DD;     // [OUTD*TWO_D]    1.05 MB
    uint*   cand  = (uint*)(wbfT + (size_t)OUTD * TWO_D); // [2*MROWS*128] 16.78 MB

    float* dout_idx  = out + NZQ;
    float* dout_loss = out + NZQ + 2 * MROWS;

    k_gemm1<<<dim3(128, 4), 256, 0, stream>>>(z, Wqa, bqa, hbuf, hbf, Rnp);
    k_cvt<<<2560, 256, 0, stream>>>(emb1, emb2, Wpq, ebf, wbfT, Ren);
    k_score_mfma<<<dim3(128, 16, 2), 512, 0, stream>>>(hbf, ebf, cand);
    k_reduce<<<1024, 256, 0, stream>>>(cand, hbuf, emb1, emb2, Rnp, Ren,
                                       dout_idx, lossb);
    k_loss2<<<64, 256, 0, stream>>>(lossb, dout_loss);
    k_gemm2m<<<dim3(128, 8), 256, 0, stream>>>(ebf, wbfT, dout_idx, bpq, out);
}

// Round 11
// 515.516 us; speedup vs baseline: 1.1344x; 1.1344x over previous
//
#include <hip/hip_runtime.h>
#include <cstdint>
#include <cstddef>

#define MROWS 16384     // B*R = 32*512
#define INDIM 1024
#define DD    256
#define TWO_D 512
#define KC    4096
#define OUTD  1024
#define NZQ   (MROWS * OUTD)   // 16777216

typedef short bfrag __attribute__((ext_vector_type(8)));   // 8 bf16 (4 VGPRs)
typedef float ffrag __attribute__((ext_vector_type(4)));   // 4 fp32 acc

__device__ __forceinline__ ushort f2bf(float f) {          // RNE f32->bf16
    uint u = __float_as_uint(f);
    return (ushort)((u + 0x7FFFu + ((u >> 16) & 1u)) >> 16);
}

// async global->LDS, 16B per lane, dest = wave-uniform base + lane*16
#define GLD16(dst, src)                                                        \
    __builtin_amdgcn_global_load_lds(                                          \
        (const __attribute__((address_space(1))) unsigned int*)(src),          \
        (__attribute__((address_space(3))) unsigned int*)(dst), 16, 0, 0)

// ---------------------------------------------------------------------------
// K1: h = z @ W_qa + b_qa (fp32, strict k-ascending FMA chain -> bit-exact;
// LOAD-BEARING). R3 structure (verified 225-229us): 128x128 tile, 8x8 micro,
// 256 thr, global_load_lds dbuf staging, 1 barrier/step.
// Epilogue emits Rnp[by][row] partial row-norm (deterministic butterfly).
// R7 lesson: no heterogeneous co-dispatch. Grid (128, 4), block 256.
// ---------------------------------------------------------------------------
__global__ __launch_bounds__(256) void k_gemm1(const float* __restrict__ z,
                                               const float* __restrict__ Wqa,
                                               const float* __restrict__ bqa,
                                               float* __restrict__ h,
                                               ushort* __restrict__ hbf,
                                               float* __restrict__ Rnp) {
    __shared__ float As[2][128][16];   // 16 KB  [buf][row][k] (k-quads swizzled)
    __shared__ float Bs[2][16][128];   // 16 KB  [buf][k][col] linear
    const int tid = threadIdx.x;
    const int l = tid & 63, w = tid >> 6;
    const int tx = tid & 15, ty = tid >> 4;
    const int rb = blockIdx.x * 128;
    const int cb = blockIdx.y * 128;

    float acc[8][8] = {};

    const int sA = 4 * ((l & 3) ^ ((l >> 4) & 3));
    const float* aA0 = z + (size_t)(rb + 32 * w + (l >> 2)) * INDIM + sA;
    const float* aA1 = aA0 + (size_t)16 * INDIM;
    const float* bB0 = Wqa + (size_t)(4 * w + (l >> 5)) * TWO_D + cb + (l & 31) * 4;
    const float* bB1 = bB0 + (size_t)2 * TWO_D;

#define STAGE(buf, k0)                                                         \
    do {                                                                       \
        GLD16(&As[buf][32 * w][0],      aA0 + (k0));                           \
        GLD16(&As[buf][32 * w + 16][0], aA1 + (k0));                           \
        GLD16(&Bs[buf][4 * w][0],       bB0 + (size_t)(k0) * TWO_D);           \
        GLD16(&Bs[buf][4 * w + 2][0],   bB1 + (size_t)(k0) * TWO_D);           \
    } while (0)

    STAGE(0, 0);
    __syncthreads();

    const int xk = ty & 3;    // read-side XOR key = (row>>2)&3 for all 8 rows
    for (int t = 0; t < 64; ++t) {
        const int cur = t & 1;
        if (t < 63) STAGE(cur ^ 1, (t + 1) * 16);   // async, lands by barrier
        #pragma unroll
        for (int q = 0; q < 4; ++q) {               // k-quad
            float fa[8][4];
            #pragma unroll
            for (int i = 0; i < 4; ++i) {
                *reinterpret_cast<float4*>(&fa[i][0]) =
                    *reinterpret_cast<const float4*>(&As[cur][ty * 4 + i][(q ^ xk) * 4]);
                *reinterpret_cast<float4*>(&fa[4 + i][0]) =
                    *reinterpret_cast<const float4*>(&As[cur][64 + ty * 4 + i][(q ^ xk) * 4]);
            }
            #pragma unroll
            for (int c = 0; c < 4; ++c) {           // kk = 4q+c, ascending
                const int kk = q * 4 + c;
                float4 b0 = *reinterpret_cast<const float4*>(&Bs[cur][kk][tx * 4]);
                float4 b1 = *reinterpret_cast<const float4*>(&Bs[cur][kk][64 + tx * 4]);
                float bv[8] = {b0.x, b0.y, b0.z, b0.w, b1.x, b1.y, b1.z, b1.w};
                #pragma unroll
                for (int i = 0; i < 8; ++i)
                    #pragma unroll
                    for (int j = 0; j < 8; ++j)
                        acc[i][j] = fmaf(fa[i][c], bv[j], acc[i][j]);
            }
        }
        __syncthreads();   // drains this wave's STAGE vmcnt + orders LDS reuse
    }
#undef STAGE

    #pragma unroll
    for (int i = 0; i < 8; ++i) {
        const int row = rb + ((i < 4) ? (ty * 4 + i) : (64 + ty * 4 + i - 4));
        float rsum = 0.f;
        #pragma unroll
        for (int jh = 0; jh < 2; ++jh) {
            const int col = cb + jh * 64 + tx * 4;
            float v0 = acc[i][jh * 4 + 0] + bqa[col + 0];
            float v1 = acc[i][jh * 4 + 1] + bqa[col + 1];
            float v2 = acc[i][jh * 4 + 2] + bqa[col + 2];
            float v3 = acc[i][jh * 4 + 3] + bqa[col + 3];
            float4 vf = {v0, v1, v2, v3};
            *reinterpret_cast<float4*>(&h[(size_t)row * TWO_D + col]) = vf;
            ushort u[4] = {f2bf(v0), f2bf(v1), f2bf(v2), f2bf(v3)};
            *reinterpret_cast<uint2*>(&hbf[(size_t)row * TWO_D + col]) =
                *reinterpret_cast<uint2*>(u);
            rsum += v0 * v0 + v1 * v1 + v2 * v2 + v3 * v3;
        }
        // 16-lane butterfly over tx (fixed order, deterministic)
        #pragma unroll
        for (int off = 1; off < 16; off <<= 1) rsum += __shfl_xor(rsum, off, 16);
        if (tx == 0) Rnp[(size_t)blockIdx.y * MROWS + row] = rsum;
    }
}

// ---------------------------------------------------------------------------
// K3: fused bf16 converts. Blocks [0,2048): emb1|emb2 -> ebf + Ren (per-wave
// one codebook row). Blocks [2048,2560): W_pq -> transposed bf16.
// Grid 2560, block 256.
// ---------------------------------------------------------------------------
__global__ __launch_bounds__(256) void k_cvt(const float* __restrict__ e1,
                                             const float* __restrict__ e2,
                                             const float* __restrict__ Wpq,
                                             ushort* __restrict__ ebf,
                                             ushort* __restrict__ wbfT,
                                             float* __restrict__ Ren) {
    const int b = blockIdx.x;
    const int tid = threadIdx.x;
    if (b < 2048) {
        const size_t v = ((size_t)b * 256 + tid) * 4;
        const size_t half = (size_t)KC * DD;
        const float* src = (v < half) ? (e1 + v) : (e2 + (v - half));
        float4 f = *reinterpret_cast<const float4*>(src);
        ebf[v + 0] = f2bf(f.x); ebf[v + 1] = f2bf(f.y);
        ebf[v + 2] = f2bf(f.z); ebf[v + 3] = f2bf(f.w);
        float ss = f.x * f.x + f.y * f.y + f.z * f.z + f.w * f.w;
        #pragma unroll
        for (int off = 32; off; off >>= 1) ss += __shfl_down(ss, off, 64);
        if ((tid & 63) == 0) Ren[b * 4 + (tid >> 6)] = ss;
    } else {
        const int e = ((b - 2048) * 256 + tid) * 4;   // 0..524284
        const int k = e >> 10, c = e & 1023;
        float4 f = *reinterpret_cast<const float4*>(&Wpq[e]);
        wbfT[(size_t)(c + 0) * TWO_D + k] = f2bf(f.x);
        wbfT[(size_t)(c + 1) * TWO_D + k] = f2bf(f.y);
        wbfT[(size_t)(c + 2) * TWO_D + k] = f2bf(f.z);
        wbfT[(size_t)(c + 3) * TWO_D + k] = f2bf(f.w);
    }
}

// ---------------------------------------------------------------------------
// K4: MFMA score pass (selection only). C[row,code] = <h_bf, e_bf>, bf16
// 16x16x32 MFMA, 128x128 block tile, K=256 in 8 chunks. global_load_lds dbuf
// staging with source-side octet swizzle (R5-verified). R8-exact version
// (best total 517.9us). R9 lesson: XCD swizzle neutral (L3-resident working
// set). R10 lesson: 128x256/512-thr tile regresses ~65us (coarser 8-wave
// barriers + lower block TLP beat the cache-traffic savings).
// cand ITEM-MAJOR: cand[(cbk*MROWS+row)*128 + seg*2]. Grid (128,32,2).
// ---------------------------------------------------------------------------
__global__ __launch_bounds__(256) void k_score_mfma(const ushort* __restrict__ hbf,
                                                    const ushort* __restrict__ ebf,
                                                    uint* __restrict__ cand) {
    __shared__ ushort Ab[2][4][128][8];   // 16 KB
    __shared__ ushort Bb[2][4][128][8];   // 16 KB
    const int tid = threadIdx.x;
    const int l = tid & 63, w = tid >> 6;
    const int rb    = blockIdx.x * 128;
    const int cbcol = blockIdx.y * 128;
    const int cbk   = blockIdx.z;
    const ushort* hb = hbf + cbk * DD;                 // row stride TWO_D
    const ushort* eb = ebf + (size_t)cbk * KC * DD;    // row stride DD

    const int ry = (w & 1) * 64;
    const int cy = (w >> 1) * 64;

    const int koct = (w ^ ((l >> 1) & 3)) * 8;
    const ushort* aS0 = hb + (size_t)(rb + l) * TWO_D + koct;
    const ushort* aS1 = hb + (size_t)(rb + 64 + l) * TWO_D + koct;
    const ushort* bS0 = eb + (size_t)(cbcol + l) * DD + koct;
    const ushort* bS1 = eb + (size_t)(cbcol + 64 + l) * DD + koct;

#define SSTAGE(buf, k0)                                                        \
    do {                                                                       \
        GLD16(&Ab[buf][w][0][0],  aS0 + (k0));                                 \
        GLD16(&Ab[buf][w][64][0], aS1 + (k0));                                 \
        GLD16(&Bb[buf][w][0][0],  bS0 + (k0));                                 \
        GLD16(&Bb[buf][w][64][0], bS1 + (k0));                                 \
    } while (0)

    ffrag acc[4][4];
    #pragma unroll
    for (int i = 0; i < 4; ++i)
        #pragma unroll
        for (int j = 0; j < 4; ++j)
            acc[i][j] = (ffrag){0.f, 0.f, 0.f, 0.f};

    SSTAGE(0, 0);
    __syncthreads();

    const int q = l >> 4, li = l & 15;
    for (int c = 0; c < 8; ++c) {
        const int cur = c & 1;
        if (c < 7) SSTAGE(cur ^ 1, (c + 1) * 32);   // async, drained by barrier
        bfrag afr[4], bfr[4];
        #pragma unroll
        for (int rf = 0; rf < 4; ++rf) {
            const int r = ry + rf * 16 + li;
            afr[rf] = *reinterpret_cast<const bfrag*>(&Ab[cur][q ^ ((r >> 1) & 3)][r][0]);
        }
        #pragma unroll
        for (int cf = 0; cf < 4; ++cf) {
            const int cc = cy + cf * 16 + li;
            bfr[cf] = *reinterpret_cast<const bfrag*>(&Bb[cur][q ^ ((cc >> 1) & 3)][cc][0]);
        }
        #pragma unroll
        for (int rf = 0; rf < 4; ++rf)
            #pragma unroll
            for (int cf = 0; cf < 4; ++cf)
                acc[rf][cf] = __builtin_amdgcn_mfma_f32_16x16x32_bf16(afr[rf], bfr[cf],
                                                                      acc[rf][cf], 0, 0, 0);
        __syncthreads();
    }
#undef SSTAGE

    const int seg = blockIdx.y * 2 + (w >> 1);
    #pragma unroll
    for (int rf = 0; rf < 4; ++rf) {
        #pragma unroll
        for (int reg = 0; reg < 4; ++reg) {
            const int row = rb + ry + rf * 16 + q * 4 + reg;
            uint k1 = 0, k2 = 0;
            #pragma unroll
            for (int cf = 0; cf < 4; ++cf) {
                float v = acc[rf][cf][reg];
                const int code = cbcol + cy + cf * 16 + li;
                uint u = __float_as_uint(v);
                u ^= (0x80000000u | (uint)((int)u >> 31));      // order-preserving flip
                const uint key = (u & 0xFFFFF000u) | (uint)code;
                if (key > k1) { k2 = k1; k1 = key; }
                else if (key > k2) { k2 = key; }
            }
            #pragma unroll
            for (int m = 1; m < 16; m <<= 1) {
                uint o1 = __shfl_xor((int)k1, m, 64);
                uint o2 = __shfl_xor((int)k2, m, 64);
                uint n1 = k1 > o1 ? k1 : o1;
                uint lo = k1 > o1 ? o1 : k1;
                uint hi2 = k2 > o2 ? k2 : o2;
                k2 = lo > hi2 ? lo : hi2;
                k1 = n1;
            }
            if (li == 0) {
                const size_t base = ((size_t)cbk * MROWS + row) * 128 + seg * 2;
                cand[base] = k1; cand[base + 1] = k2;
            }
        }
    }
}

// ---------------------------------------------------------------------------
// K5: reduce. One wave = 8 items x 8 candidate lanes (R6-verified). Per item:
// 128 contiguous keys -> top-8 via 8 rounds; each lane one exact fp32 dot
// (float4 loads, x,y,z,w fmaf order = sequential d-ascending chain).
// Rn = Rnp[2cb]+Rnp[2cb+1] (fixed order). d = Rn - 2M; lexicographic
// (d,code) min. Winner emits lossb = d + Ren[code]. Grid 1024, block 256.
// ---------------------------------------------------------------------------
__global__ __launch_bounds__(256) void k_reduce(const uint* __restrict__ cand,
                                                const float* __restrict__ h,
                                                const float* __restrict__ emb1,
                                                const float* __restrict__ emb2,
                                                const float* __restrict__ Rnp,
                                                const float* __restrict__ Ren,
                                                float* __restrict__ dout_idx,
                                                float* __restrict__ lossb) {
    const int tid = threadIdx.x;
    const int l = tid & 63, w = tid >> 6;
    const int g = l & 7;                       // candidate slot within item
    const int item = blockIdx.x * 32 + w * 8 + (l >> 3);
    const int cb  = item >> 14;
    const int row = item & (MROWS - 1);

    const uint* kp = cand + (size_t)item * 128 + g * 16;
    uint k[16];
    #pragma unroll
    for (int j = 0; j < 4; ++j) {
        uint4 v = *reinterpret_cast<const uint4*>(kp + j * 4);
        k[j * 4 + 0] = v.x; k[j * 4 + 1] = v.y;
        k[j * 4 + 2] = v.z; k[j * 4 + 3] = v.w;
    }

    uint mykey = 0;
    #pragma unroll
    for (int t = 0; t < 8; ++t) {
        uint m = k[0];
        #pragma unroll
        for (int j = 1; j < 16; ++j) m = k[j] > m ? k[j] : m;
        #pragma unroll
        for (int off = 1; off < 8; off <<= 1) {
            uint o = (uint)__shfl_xor((int)m, off, 64);
            m = o > m ? o : m;
        }
        #pragma unroll
        for (int j = 0; j < 16; ++j) k[j] = (k[j] == m) ? 0u : k[j];
        if (g == t) mykey = m;
    }

    const int code = (int)(mykey & 0xFFFu);
    const float* hr = h + (size_t)row * TWO_D + cb * DD;
    const float* er = (cb ? emb2 : emb1) + (size_t)code * DD;
    float M = 0.f;
    for (int d = 0; d < DD; d += 4) {        // sequential chain, vector loads
        float4 a = *reinterpret_cast<const float4*>(hr + d);
        float4 b = *reinterpret_cast<const float4*>(er + d);
        M = fmaf(a.x, b.x, M); M = fmaf(a.y, b.y, M);
        M = fmaf(a.z, b.z, M); M = fmaf(a.w, b.w, M);
    }
    const float Rn = Rnp[(size_t)(2 * cb) * MROWS + row] +
                     Rnp[(size_t)(2 * cb + 1) * MROWS + row];
    float dd = Rn - 2.0f * M;
    int c2 = code;
    #pragma unroll
    for (int off = 1; off < 8; off <<= 1) {
        float od = __shfl_xor(dd, off, 64);
        int   oc = __shfl_xor(c2, off, 64);
        if (od < dd || (od == dd && oc < c2)) { dd = od; c2 = oc; }
    }
    if (g == 0) {
        dout_idx[cb * MROWS + row] = (float)c2;
        lossb[cb * MROWS + row] = dd + Ren[cb * KC + c2];
    }
}

// ---------------------------------------------------------------------------
// K6: combine per-half loss partials. Grid 64, block 256.
// ---------------------------------------------------------------------------
__global__ __launch_bounds__(256) void k_loss2(const float* __restrict__ lossb,
                                               float* __restrict__ dout_loss) {
    const int r = blockIdx.x * 256 + threadIdx.x;
    dout_loss[r] = (lossb[r] + lossb[MROWS + r]) * (0.625f / 256.0f);
}

// ---------------------------------------------------------------------------
// K7: out = gather(e_bf, idx) @ W_pq_bf + b_pq via MFMA (bf16 in, fp32 out).
// global_load_lds dbuf pipeline, source-side octet swizzle (R5-verified).
// Grid (128, 8), block 256.
// ---------------------------------------------------------------------------
__global__ __launch_bounds__(256) void k_gemm2m(const ushort* __restrict__ ebf,
                                                const ushort* __restrict__ wbfT,
                                                const float* __restrict__ idxf,
                                                const float* __restrict__ bpq,
                                                float* __restrict__ out) {
    __shared__ ushort Ab[2][4][128][8];   // 16 KB
    __shared__ ushort Bb[2][4][128][8];   // 16 KB
    const int tid = threadIdx.x;
    const int l = tid & 63, w = tid >> 6;
    const int rb    = blockIdx.x * 128;
    const int cbcol = blockIdx.y * 128;
    const int ry = (w & 1) * 64;
    const int cy = (w >> 1) * 64;
    const ushort* e1 = ebf;
    const ushort* e2 = ebf + (size_t)KC * DD;

    const int ia0 = (int)idxf[rb + l];
    const int ia1 = (int)idxf[rb + 64 + l];
    const int ib0 = (int)idxf[MROWS + rb + l];
    const int ib1 = (int)idxf[MROWS + rb + 64 + l];

    const int koct = (w ^ ((l >> 1) & 3)) * 8;
    const ushort* aA0 = e1 + (size_t)ia0 * DD + koct;   // half 0, rows it=0
    const ushort* aA1 = e1 + (size_t)ia1 * DD + koct;   // half 0, rows it=1
    const ushort* aB0 = e2 + (size_t)ib0 * DD + koct;   // half 1
    const ushort* aB1 = e2 + (size_t)ib1 * DD + koct;
    const ushort* bS0 = wbfT + (size_t)(cbcol + l) * TWO_D + koct;
    const ushort* bS1 = wbfT + (size_t)(cbcol + 64 + l) * TWO_D + koct;

#define GSTAGE(buf, c)                                                         \
    do {                                                                       \
        const int cbs_ = (c) >> 3;                                             \
        const int ka_  = ((c) * 32) & 255;                                     \
        GLD16(&Ab[buf][w][0][0],  (cbs_ ? aB0 : aA0) + ka_);                   \
        GLD16(&Ab[buf][w][64][0], (cbs_ ? aB1 : aA1) + ka_);                   \
        GLD16(&Bb[buf][w][0][0],  bS0 + (c) * 32);                             \
        GLD16(&Bb[buf][w][64][0], bS1 + (c) * 32);                             \
    } while (0)

    ffrag acc[4][4];
    #pragma unroll
    for (int i = 0; i < 4; ++i)
        #pragma unroll
        for (int j = 0; j < 4; ++j)
            acc[i][j] = (ffrag){0.f, 0.f, 0.f, 0.f};

    GSTAGE(0, 0);
    __syncthreads();

    const int q = l >> 4, li = l & 15;
    for (int c = 0; c < 16; ++c) {
        const int cur = c & 1;
        if (c < 15) GSTAGE(cur ^ 1, c + 1);   // async, drained by barrier
        bfrag afr[4], bfr[4];
        #pragma unroll
        for (int rf = 0; rf < 4; ++rf) {
            const int r = ry + rf * 16 + li;
            afr[rf] = *reinterpret_cast<const bfrag*>(&Ab[cur][q ^ ((r >> 1) & 3)][r][0]);
        }
        #pragma unroll
        for (int cf = 0; cf < 4; ++cf) {
            const int cc = cy + cf * 16 + li;
            bfr[cf] = *reinterpret_cast<const bfrag*>(&Bb[cur][q ^ ((cc >> 1) & 3)][cc][0]);
        }
        #pragma unroll
        for (int rf = 0; rf < 4; ++rf)
            #pragma unroll
            for (int cf = 0; cf < 4; ++cf)
                acc[rf][cf] = __builtin_amdgcn_mfma_f32_16x16x32_bf16(afr[rf], bfr[cf],
                                                                      acc[rf][cf], 0, 0, 0);
        __syncthreads();
    }
#undef GSTAGE

    #pragma unroll
    for (int rf = 0; rf < 4; ++rf) {
        #pragma unroll
        for (int reg = 0; reg < 4; ++reg) {
            const int row = rb + ry + rf * 16 + q * 4 + reg;
            #pragma unroll
            for (int cf = 0; cf < 4; ++cf) {
                const int col = cbcol + cy + cf * 16 + li;
                out[(size_t)row * OUTD + col] = acc[rf][cf][reg] + bpq[col];
            }
        }
    }
}

// ---------------------------------------------------------------------------
extern "C" void kernel_launch(void* const* d_in, const int* in_sizes, int n_in,
                              void* d_out, int out_size, void* d_ws, size_t ws_size,
                              hipStream_t stream) {
    const float* z    = (const float*)d_in[0];
    const float* Wqa  = (const float*)d_in[1];
    const float* bqa  = (const float*)d_in[2];
    const float* emb1 = (const float*)d_in[3];
    const float* emb2 = (const float*)d_in[4];
    const float* Wpq  = (const float*)d_in[5];
    const float* bpq  = (const float*)d_in[6];
    float* out = (float*)d_out;

    const size_t H = (size_t)MROWS * TWO_D;        // 8,388,608
    float*  hbuf  = (float*)d_ws;                  // [H]            33.55 MB
    float*  Rnp   = hbuf + H;                      // [4*MROWS]       0.26 MB
    float*  lossb = Rnp + 4 * MROWS;               // [2*MROWS]       0.13 MB
    float*  Ren   = lossb + 2 * MROWS;             // [2*KC]          0.03 MB
    ushort* hbf   = (ushort*)(Ren + 2 * KC);       // [H]            16.78 MB
    ushort* ebf   = hbf + H;                       // [2*KC*DD]       4.19 MB
    ushort* wbfT  = ebf + 2 * (size_t)KC * DD;     // [OUTD*TWO_D]    1.05 MB
    uint*   cand  = (uint*)(wbfT + (size_t)OUTD * TWO_D); // [2*MROWS*128] 16.78 MB

    float* dout_idx  = out + NZQ;
    float* dout_loss = out + NZQ + 2 * MROWS;

    k_gemm1<<<dim3(128, 4), 256, 0, stream>>>(z, Wqa, bqa, hbuf, hbf, Rnp);
    k_cvt<<<2560, 256, 0, stream>>>(emb1, emb2, Wpq, ebf, wbfT, Ren);
    k_score_mfma<<<dim3(128, 32, 2), 256, 0, stream>>>(hbf, ebf, cand);
    k_reduce<<<1024, 256, 0, stream>>>(cand, hbuf, emb1, emb2, Rnp, Ren,
                                       dout_idx, lossb);
    k_loss2<<<64, 256, 0, stream>>>(lossb, dout_loss);
    k_gemm2m<<<dim3(128, 8), 256, 0, stream>>>(ebf, wbfT, dout_idx, bpq, out);
}